// Round 1
// baseline (282.662 us; speedup 1.0000x reference)
//
#include <hip/hip_runtime.h>
#include <hip/hip_bf16.h>

#define B_ 8
#define N_ 256
#define H_ 128
#define E_ 32

typedef __bf16 bf16x8 __attribute__((ext_vector_type(8)));
typedef float f32x4 __attribute__((ext_vector_type(4)));

// round-to-nearest-even fp32 -> bf16 (3 VALU ops, no NaN handling needed for
// finite random inputs)
static __device__ __forceinline__ __bf16 f2bf(float f) {
    union { float f; unsigned int u; } a;
    a.f = f;
    const unsigned int r = a.u + 0x7FFFu + ((a.u >> 16) & 1u);
    union { unsigned short s; __bf16 b; } o;
    o.s = (unsigned short)(r >> 16);
    return o.b;
}

// Kernel 1: per (b,i) workgroup computes
//   h[b,i,:] = x[b,i,:] + sum_j adj[b,i,j] * relu(x[b,j,:] + e[b,i,j,:]@We + be)
// GEMM per WG: M=j(256) x N=h(128), K=32 == one mfma_f32_16x16x32_bf16 in K.
// 4 waves; wave w handles j-chunks {w, w+4, w+8, w+12} (16 rows each).
// A-fragment (A[m=col][k=quad*8+i]) loaded directly from global: lane reads 8
// contiguous fp32 (two float4) -> wave union is the contiguous 2 KiB j-block.
// B-fragment (B[k=quad*8+i][n=col]) = We, resident in 32 VGPRs for the whole
// kernel. C layout: row = quad*4 + reg, col = lane&15 (m89/m91-verified).
__global__ __launch_bounds__(256, 4) void agg_kernel(
    const float* __restrict__ x, const int* __restrict__ adj,
    const float* __restrict__ e, const float* __restrict__ We,
    const float* __restrict__ be, float* __restrict__ hout)
{
    __shared__ float red[4][128];
    const int bi   = blockIdx.x;      // b*256 + i
    const int b    = bi >> 8;
    const int w    = threadIdx.x >> 6;
    const int lane = threadIdx.x & 63;
    const int quad = lane >> 4;
    const int col  = lane & 15;

    // Preload all of We as B-fragments (8 h-tiles x 8 bf16 = 32 VGPRs) + be.
    bf16x8 bw[8];
    float  bef[8];
#pragma unroll
    for (int ht = 0; ht < 8; ++ht) {
#pragma unroll
        for (int kk = 0; kk < 8; ++kk)
            bw[ht][kk] = f2bf(We[(quad * 8 + kk) * H_ + ht * 16 + col]);
        bef[ht] = be[ht * 16 + col];
    }

    float psum[8];
#pragma unroll
    for (int ht = 0; ht < 8; ++ht) psum[ht] = 0.0f;

    const size_t ebase   = (size_t)bi * (N_ * E_);
    const size_t adjbase = (size_t)bi * N_;
    const f32x4 zero4 = {0.0f, 0.0f, 0.0f, 0.0f};

#pragma unroll
    for (int c = 0; c < 4; ++c) {
        const int j0 = (c * 4 + w) * 16;

        // A fragment: e[b,i, j0+col, quad*8 .. +7]
        const float* ap = e + ebase + (size_t)(j0 + col) * E_ + quad * 8;
        const float4 a0 = *(const float4*)ap;
        const float4 a1 = *(const float4*)(ap + 4);
        bf16x8 af;
        af[0] = f2bf(a0.x); af[1] = f2bf(a0.y); af[2] = f2bf(a0.z); af[3] = f2bf(a0.w);
        af[4] = f2bf(a1.x); af[5] = f2bf(a1.y); af[6] = f2bf(a1.z); af[7] = f2bf(a1.w);

        f32x4 acc[8];
#pragma unroll
        for (int ht = 0; ht < 8; ++ht)
            acc[ht] = __builtin_amdgcn_mfma_f32_16x16x32_bf16(af, bw[ht], zero4, 0, 0, 0);

        // Epilogue: relu(e_h + x[b,j,:] + be) * adj, accumulate over this
        // lane's 4 j-rows into per-lane psum (one per h-tile).
#pragma unroll
        for (int r = 0; r < 4; ++r) {
            const int j = j0 + quad * 4 + r;
            const float adjf = adj[adjbase + j] ? 1.0f : 0.0f;
            const float* xr = x + ((size_t)(b * N_ + j)) * H_ + col;
#pragma unroll
            for (int ht = 0; ht < 8; ++ht) {
                const float v = acc[ht][r] + xr[ht * 16] + bef[ht];
                psum[ht] += adjf * fmaxf(v, 0.0f);
            }
        }
    }

    // Reduce across the 4 quads (same col, different j) in-register, then
    // across the 4 waves via LDS.
#pragma unroll
    for (int ht = 0; ht < 8; ++ht) {
        float v = psum[ht];
        v += __shfl_xor(v, 16);
        v += __shfl_xor(v, 32);
        if (lane < 16) red[w][ht * 16 + lane] = v;
    }
    __syncthreads();
    const int tid = threadIdx.x;
    if (tid < 128) {
        const float aggv = red[0][tid] + red[1][tid] + red[2][tid] + red[3][tid];
        hout[(size_t)bi * H_ + tid] = aggv + x[(size_t)bi * H_ + tid];
    }
}

// Kernel 2: out = relu(h @ W1 + b1) @ W2 + b2, fp32 vector.
// 256 WGs x 8 rows each; h rows + layer-1 activations staged in LDS,
// weights streamed (broadcast across WGs -> L2-resident).
__global__ __launch_bounds__(256) void mlp_kernel(
    const float* __restrict__ hin, const float* __restrict__ W1,
    const float* __restrict__ b1, const float* __restrict__ W2,
    const float* __restrict__ b2, float* __restrict__ out)
{
    __shared__ float hs[8][128];
    __shared__ float ts[8][256];
    const int tid = threadIdx.x;
    const int r0  = blockIdx.x * 8;

    for (int idx = tid; idx < 8 * 128; idx += 256)
        hs[idx >> 7][idx & 127] = hin[(size_t)r0 * 128 + idx];
    __syncthreads();

    // Layer 1: thread tid owns output column c = tid for all 8 rows.
    {
        const int cg = tid;
        const float bb = b1[cg];
        float acc[8];
#pragma unroll
        for (int r = 0; r < 8; ++r) acc[r] = bb;
        for (int k0 = 0; k0 < 128; k0 += 4) {
            const float w0 = W1[(k0 + 0) * 256 + cg];
            const float w1 = W1[(k0 + 1) * 256 + cg];
            const float w2 = W1[(k0 + 2) * 256 + cg];
            const float w3 = W1[(k0 + 3) * 256 + cg];
#pragma unroll
            for (int r = 0; r < 8; ++r) {
                const float4 hv = *(const float4*)&hs[r][k0];   // LDS broadcast
                acc[r] += hv.x * w0 + hv.y * w1 + hv.z * w2 + hv.w * w3;
            }
        }
#pragma unroll
        for (int r = 0; r < 8; ++r) ts[r][cg] = fmaxf(acc[r], 0.0f);
    }
    __syncthreads();

    // Layer 2: thread owns column c = tid&127 for 4 rows (half = tid>>7).
    {
        const int c    = tid & 127;
        const int half = tid >> 7;
        const float bb = b2[c];
        float acc[4];
#pragma unroll
        for (int r = 0; r < 4; ++r) acc[r] = bb;
        for (int k0 = 0; k0 < 256; k0 += 4) {
            const float w0 = W2[(k0 + 0) * 128 + c];
            const float w1 = W2[(k0 + 1) * 128 + c];
            const float w2 = W2[(k0 + 2) * 128 + c];
            const float w3 = W2[(k0 + 3) * 128 + c];
#pragma unroll
            for (int r = 0; r < 4; ++r) {
                const int row = half * 4 + r;
                const float4 tv = *(const float4*)&ts[row][k0];  // 2-way bcast
                acc[r] += tv.x * w0 + tv.y * w1 + tv.z * w2 + tv.w * w3;
            }
        }
#pragma unroll
        for (int r = 0; r < 4; ++r)
            out[(size_t)(r0 + half * 4 + r) * 128 + c] = acc[r];
    }
}

extern "C" void kernel_launch(void* const* d_in, const int* in_sizes, int n_in,
                              void* d_out, int out_size, void* d_ws, size_t ws_size,
                              hipStream_t stream) {
    const float* x   = (const float*)d_in[0];
    const int*   adj = (const int*)  d_in[1];
    const float* e   = (const float*)d_in[2];
    const float* We  = (const float*)d_in[3];
    const float* be  = (const float*)d_in[4];
    const float* W1  = (const float*)d_in[5];
    const float* b1  = (const float*)d_in[6];
    const float* W2  = (const float*)d_in[7];
    const float* b2  = (const float*)d_in[8];
    float* out = (float*)d_out;
    float* hws = (float*)d_ws;   // [B*N, H] = 1 MiB fp32 intermediate

    agg_kernel<<<dim3(B_ * N_), dim3(256), 0, stream>>>(x, adj, e, We, be, hws);
    mlp_kernel<<<dim3(B_ * N_ / 8), dim3(256), 0, stream>>>(hws, W1, b1, W2, b2, out);
}

// Round 2
// 274.052 us; speedup vs baseline: 1.0314x; 1.0314x over previous
//
#include <hip/hip_runtime.h>
#include <hip/hip_bf16.h>

#define B_ 8
#define N_ 256
#define H_ 128
#define E_ 32

typedef __bf16 bf16x8 __attribute__((ext_vector_type(8)));
typedef float f32x4 __attribute__((ext_vector_type(4)));

// round-to-nearest-even fp32 -> bf16
static __device__ __forceinline__ __bf16 f2bf(float f) {
    union { float f; unsigned int u; } a;
    a.f = f;
    const unsigned int r = a.u + 0x7FFFu + ((a.u >> 16) & 1u);
    union { unsigned short s; __bf16 b; } o;
    o.s = (unsigned short)(r >> 16);
    return o.b;
}

// Kernel 1: per (b,i) workgroup computes
//   h[b,i,:] = x[b,i,:] + sum_j adj[b,i,j] * relu(x[b,j,:] + e[b,i,j,:]@We + be)
// GEMM per WG: M=j(256) x N=h(128), K=32 == one mfma_f32_16x16x32_bf16.
// 4 waves; wave w handles j-chunks {w, w+4, w+8, w+12} (16 rows each).
// Register-pressure control (round-1 spilled at VGPR=64: 284 MB scratch
// writes): h-tiles processed in 2 groups of 4 so only 16 acc regs live;
// __launch_bounds__(256,3) gives the allocator ~170 regs of headroom.
__global__ __launch_bounds__(256, 3) void agg_kernel(
    const float* __restrict__ x, const int* __restrict__ adj,
    const float* __restrict__ e, const float* __restrict__ We,
    const float* __restrict__ be, float* __restrict__ hout)
{
    __shared__ float red[4][128];
    const int bi   = blockIdx.x;      // b*256 + i
    const int b    = bi >> 8;
    const int w    = threadIdx.x >> 6;
    const int lane = threadIdx.x & 63;
    const int quad = lane >> 4;
    const int col  = lane & 15;

    // Preload all of We as B-fragments (8 h-tiles x 8 bf16 = 32 VGPRs) + be.
    bf16x8 bw[8];
    float  bef[8];
#pragma unroll
    for (int ht = 0; ht < 8; ++ht) {
#pragma unroll
        for (int kk = 0; kk < 8; ++kk)
            bw[ht][kk] = f2bf(We[(quad * 8 + kk) * H_ + ht * 16 + col]);
        bef[ht] = be[ht * 16 + col];
    }

    float psum[8];
#pragma unroll
    for (int ht = 0; ht < 8; ++ht) psum[ht] = 0.0f;

    const size_t ebase   = (size_t)bi * (N_ * E_);
    const size_t adjbase = (size_t)bi * N_;
    const f32x4 zero4 = {0.0f, 0.0f, 0.0f, 0.0f};

#pragma unroll
    for (int c = 0; c < 4; ++c) {
        const int j0 = (c * 4 + w) * 16;

        // A fragment: e[b,i, j0+col, quad*8 .. +7] (wave union = contiguous 2 KiB)
        const float* ap = e + ebase + (size_t)(j0 + col) * E_ + quad * 8;
        const float4 a0 = *(const float4*)ap;
        const float4 a1 = *(const float4*)(ap + 4);
        bf16x8 af;
        af[0] = f2bf(a0.x); af[1] = f2bf(a0.y); af[2] = f2bf(a0.z); af[3] = f2bf(a0.w);
        af[4] = f2bf(a1.x); af[5] = f2bf(a1.y); af[6] = f2bf(a1.z); af[7] = f2bf(a1.w);

        // adj mask for this lane's 4 j-rows, hoisted out of the ht groups.
        float adjf[4];
        const int jr = j0 + quad * 4;
#pragma unroll
        for (int r = 0; r < 4; ++r)
            adjf[r] = adj[adjbase + jr + r] ? 1.0f : 0.0f;

        const float* xrow = x + ((size_t)(b * N_ + jr)) * H_ + col;

        // Two groups of 4 h-tiles: 4 independent MFMAs in flight, then their
        // epilogues; caps live acc regs at 16.
#pragma unroll
        for (int g = 0; g < 2; ++g) {
            f32x4 acc[4];
#pragma unroll
            for (int t = 0; t < 4; ++t)
                acc[t] = __builtin_amdgcn_mfma_f32_16x16x32_bf16(af, bw[g * 4 + t], zero4, 0, 0, 0);
#pragma unroll
            for (int r = 0; r < 4; ++r) {
                const float* xr = xrow + (size_t)r * H_;
#pragma unroll
                for (int t = 0; t < 4; ++t) {
                    const int ht = g * 4 + t;
                    const float v = acc[t][r] + xr[ht * 16] + bef[ht];
                    psum[ht] += adjf[r] * fmaxf(v, 0.0f);
                }
            }
        }
    }

    // Reduce across the 4 quads (same col, different j) in-register, then
    // across the 4 waves via LDS.
#pragma unroll
    for (int ht = 0; ht < 8; ++ht) {
        float v = psum[ht];
        v += __shfl_xor(v, 16);
        v += __shfl_xor(v, 32);
        if (lane < 16) red[w][ht * 16 + lane] = v;
    }
    __syncthreads();
    const int tid = threadIdx.x;
    if (tid < 128) {
        const float aggv = red[0][tid] + red[1][tid] + red[2][tid] + red[3][tid];
        hout[(size_t)bi * H_ + tid] = aggv + x[(size_t)bi * H_ + tid];
    }
}

// Kernel 2: out = relu(h @ W1 + b1) @ W2 + b2, fp32 vector.
// 512 WGs x 4 rows each (was 256x8 = 1 WG/CU latency-bound); weights stream
// from L2 (W1+W2 = 384 KB, broadcast across WGs).
__global__ __launch_bounds__(256) void mlp_kernel(
    const float* __restrict__ hin, const float* __restrict__ W1,
    const float* __restrict__ b1, const float* __restrict__ W2,
    const float* __restrict__ b2, float* __restrict__ out)
{
    __shared__ float hs[4][128];
    __shared__ float ts[4][256];
    const int tid = threadIdx.x;
    const int r0  = blockIdx.x * 4;

    for (int idx = tid; idx < 4 * 128; idx += 256)
        hs[idx >> 7][idx & 127] = hin[(size_t)r0 * 128 + idx];
    __syncthreads();

    // Layer 1: thread tid owns output column c = tid for 4 rows.
    {
        const int cg = tid;
        const float bb = b1[cg];
        float acc[4];
#pragma unroll
        for (int r = 0; r < 4; ++r) acc[r] = bb;
        for (int k0 = 0; k0 < 128; k0 += 4) {
            const float w0 = W1[(k0 + 0) * 256 + cg];
            const float w1 = W1[(k0 + 1) * 256 + cg];
            const float w2 = W1[(k0 + 2) * 256 + cg];
            const float w3 = W1[(k0 + 3) * 256 + cg];
#pragma unroll
            for (int r = 0; r < 4; ++r) {
                const float4 hv = *(const float4*)&hs[r][k0];   // LDS broadcast
                acc[r] += hv.x * w0 + hv.y * w1 + hv.z * w2 + hv.w * w3;
            }
        }
#pragma unroll
        for (int r = 0; r < 4; ++r) ts[r][cg] = fmaxf(acc[r], 0.0f);
    }
    __syncthreads();

    // Layer 2: thread owns column c = tid&127 for 2 rows (pair = tid>>7).
    {
        const int c    = tid & 127;
        const int pair = tid >> 7;
        const float bb = b2[c];
        float acc[2];
#pragma unroll
        for (int r = 0; r < 2; ++r) acc[r] = bb;
        for (int k0 = 0; k0 < 256; k0 += 4) {
            const float w0 = W2[(k0 + 0) * 128 + c];
            const float w1 = W2[(k0 + 1) * 128 + c];
            const float w2 = W2[(k0 + 2) * 128 + c];
            const float w3 = W2[(k0 + 3) * 128 + c];
#pragma unroll
            for (int r = 0; r < 2; ++r) {
                const int row = pair * 2 + r;
                const float4 tv = *(const float4*)&ts[row][k0];
                acc[r] += tv.x * w0 + tv.y * w1 + tv.z * w2 + tv.w * w3;
            }
        }
#pragma unroll
        for (int r = 0; r < 2; ++r)
            out[(size_t)(r0 + pair * 2 + r) * 128 + c] = acc[r];
    }
}

extern "C" void kernel_launch(void* const* d_in, const int* in_sizes, int n_in,
                              void* d_out, int out_size, void* d_ws, size_t ws_size,
                              hipStream_t stream) {
    const float* x   = (const float*)d_in[0];
    const int*   adj = (const int*)  d_in[1];
    const float* e   = (const float*)d_in[2];
    const float* We  = (const float*)d_in[3];
    const float* be  = (const float*)d_in[4];
    const float* W1  = (const float*)d_in[5];
    const float* b1  = (const float*)d_in[6];
    const float* W2  = (const float*)d_in[7];
    const float* b2  = (const float*)d_in[8];
    float* out = (float*)d_out;
    float* hws = (float*)d_ws;   // [B*N, H] = 1 MiB fp32 intermediate

    agg_kernel<<<dim3(B_ * N_), dim3(256), 0, stream>>>(x, adj, e, We, be, hws);
    mlp_kernel<<<dim3(B_ * N_ / 4), dim3(256), 0, stream>>>(hws, W1, b1, W2, b2, out);
}

// Round 3
// 167.046 us; speedup vs baseline: 1.6921x; 1.6406x over previous
//
#include <hip/hip_runtime.h>
#include <hip/hip_bf16.h>

#define B_ 8
#define N_ 256
#define H_ 128
#define E_ 32

typedef __bf16 bf16x8 __attribute__((ext_vector_type(8)));
typedef float f32x4 __attribute__((ext_vector_type(4)));

// round-to-nearest-even fp32 -> bf16
static __device__ __forceinline__ __bf16 f2bf(float f) {
    union { float f; unsigned int u; } a;
    a.f = f;
    const unsigned int r = a.u + 0x7FFFu + ((a.u >> 16) & 1u);
    union { unsigned short s; __bf16 b; } o;
    o.s = (unsigned short)(r >> 16);
    return o.b;
}

// Fully fused kernel: one WG per (b,i).
// Phase 1 (aggregate, bf16 MFMA):
//   h[:] = x[b,i,:] + sum_j adj[b,i,j]*relu(x[b,j,:] + e[b,i,j,:]@We + be)
// Phase 2 (MLP, fp32 from LDS): out[b,i,:] = relu(h@W1+b1)@W2 + b2
//
// Register-pressure history: gfx950 unified-file compiler splits the
// launch-bounds budget 50/50 arch/AGPR (r1: (256,4)->64 arch, r2: (256,3)->84
// arch — both spilled, 190-280 MB scratch traffic). Arch live set ~100 regs
// => need >=200 budget => __launch_bounds__(256,2) (256 regs -> 128 arch).
__global__ __launch_bounds__(256, 2) void fused_kernel(
    const float* __restrict__ x, const int* __restrict__ adj,
    const float* __restrict__ e, const float* __restrict__ We,
    const float* __restrict__ be, const float* __restrict__ W1,
    const float* __restrict__ b1, const float* __restrict__ W2,
    const float* __restrict__ b2, float* __restrict__ out)
{
    __shared__ float red[4][128];
    __shared__ float hvec[128];
    __shared__ float ts[256];
    __shared__ float part[256];

    const int bi   = blockIdx.x;      // b*256 + i
    const int b    = bi >> 8;
    const int tid  = threadIdx.x;
    const int w    = tid >> 6;
    const int lane = tid & 63;
    const int quad = lane >> 4;
    const int col  = lane & 15;

    // Preload all of We as B-fragments (8 h-tiles x 8 bf16 = 32 VGPRs) + be.
    bf16x8 bw[8];
    float  bef[8];
#pragma unroll
    for (int ht = 0; ht < 8; ++ht) {
#pragma unroll
        for (int kk = 0; kk < 8; ++kk)
            bw[ht][kk] = f2bf(We[(quad * 8 + kk) * H_ + ht * 16 + col]);
        bef[ht] = be[ht * 16 + col];
    }

    float psum[8];
#pragma unroll
    for (int ht = 0; ht < 8; ++ht) psum[ht] = 0.0f;

    const size_t ebase   = (size_t)bi * (N_ * E_);
    const size_t adjbase = (size_t)bi * N_;
    const f32x4 zero4 = {0.0f, 0.0f, 0.0f, 0.0f};

#pragma unroll
    for (int c = 0; c < 4; ++c) {
        const int j0 = (c * 4 + w) * 16;

        // A fragment: e[b,i, j0+col, quad*8 .. +7] (wave union = contiguous 2 KiB)
        const float* ap = e + ebase + (size_t)(j0 + col) * E_ + quad * 8;
        const float4 a0 = *(const float4*)ap;
        const float4 a1 = *(const float4*)(ap + 4);
        bf16x8 af;
        af[0] = f2bf(a0.x); af[1] = f2bf(a0.y); af[2] = f2bf(a0.z); af[3] = f2bf(a0.w);
        af[4] = f2bf(a1.x); af[5] = f2bf(a1.y); af[6] = f2bf(a1.z); af[7] = f2bf(a1.w);

        // adj mask for this lane's 4 j-rows.
        float adjf[4];
        const int jr = j0 + quad * 4;
#pragma unroll
        for (int r = 0; r < 4; ++r)
            adjf[r] = adj[adjbase + jr + r] ? 1.0f : 0.0f;

        const float* xrow = x + ((size_t)(b * N_ + jr)) * H_ + col;

        // Two groups of 4 h-tiles (16 acc regs live per group).
#pragma unroll
        for (int g = 0; g < 2; ++g) {
            f32x4 acc[4];
#pragma unroll
            for (int t = 0; t < 4; ++t)
                acc[t] = __builtin_amdgcn_mfma_f32_16x16x32_bf16(af, bw[g * 4 + t], zero4, 0, 0, 0);
#pragma unroll
            for (int r = 0; r < 4; ++r) {
                const float* xr = xrow + (size_t)r * H_;
#pragma unroll
                for (int t = 0; t < 4; ++t) {
                    const int ht = g * 4 + t;
                    const float v = acc[t][r] + xr[ht * 16] + bef[ht];
                    psum[ht] += adjf[r] * fmaxf(v, 0.0f);
                }
            }
        }
    }

    // Reduce across the 4 quads (same col, different j) in-register, then
    // across the 4 waves via LDS; h = agg + x stays in LDS.
#pragma unroll
    for (int ht = 0; ht < 8; ++ht) {
        float v = psum[ht];
        v += __shfl_xor(v, 16);
        v += __shfl_xor(v, 32);
        if (lane < 16) red[w][ht * 16 + lane] = v;
    }
    __syncthreads();
    if (tid < 128) {
        const float aggv = red[0][tid] + red[1][tid] + red[2][tid] + red[3][tid];
        hvec[tid] = aggv + x[(size_t)bi * H_ + tid];
    }
    __syncthreads();

    // ---- MLP phase (fp32), weights stream from L2 (384 KB, shared by all WGs)
    // Layer 1: thread tid owns output column tid (128 MACs, hvec broadcast).
    {
        const int c = tid;
        float a0 = 0.f, a1 = 0.f, a2 = 0.f, a3 = 0.f;
        for (int k = 0; k < 128; k += 4) {
            a0 += hvec[k + 0] * W1[(k + 0) * 256 + c];
            a1 += hvec[k + 1] * W1[(k + 1) * 256 + c];
            a2 += hvec[k + 2] * W1[(k + 2) * 256 + c];
            a3 += hvec[k + 3] * W1[(k + 3) * 256 + c];
        }
        ts[c] = fmaxf((a0 + a1) + (a2 + a3) + b1[c], 0.0f);
    }
    __syncthreads();

    // Layer 2: two threads per output column, k split 128/128.
    {
        const int c    = tid & 127;
        const int kb   = (tid >> 7) * 128;
        float a0 = 0.f, a1 = 0.f, a2 = 0.f, a3 = 0.f;
        for (int k = 0; k < 128; k += 4) {
            a0 += ts[kb + k + 0] * W2[(kb + k + 0) * 128 + c];
            a1 += ts[kb + k + 1] * W2[(kb + k + 1) * 128 + c];
            a2 += ts[kb + k + 2] * W2[(kb + k + 2) * 128 + c];
            a3 += ts[kb + k + 3] * W2[(kb + k + 3) * 128 + c];
        }
        part[tid] = (a0 + a1) + (a2 + a3);
    }
    __syncthreads();
    if (tid < 128)
        out[(size_t)bi * H_ + tid] = part[tid] + part[tid + 128] + b2[tid];
}

extern "C" void kernel_launch(void* const* d_in, const int* in_sizes, int n_in,
                              void* d_out, int out_size, void* d_ws, size_t ws_size,
                              hipStream_t stream) {
    const float* x   = (const float*)d_in[0];
    const int*   adj = (const int*)  d_in[1];
    const float* e   = (const float*)d_in[2];
    const float* We  = (const float*)d_in[3];
    const float* be  = (const float*)d_in[4];
    const float* W1  = (const float*)d_in[5];
    const float* b1  = (const float*)d_in[6];
    const float* W2  = (const float*)d_in[7];
    const float* b2  = (const float*)d_in[8];
    float* out = (float*)d_out;

    fused_kernel<<<dim3(B_ * N_), dim3(256), 0, stream>>>(
        x, adj, e, We, be, W1, b1, W2, b2, out);
}